// Round 5
// baseline (63.270 us; speedup 1.0000x reference)
//
#include <hip/hip_runtime.h>
#include <math.h>

#define NPTS   8192
#define BITS   64
#define NCLS   101
#define WT     32                        // wave tile (one 32x32 MFMA tile per wave)
#define NT2    (NPTS / WT)               // 256 tiles per dim
#define NPW    (NT2 * (NT2 + 1) / 2)     // 32896 upper-tri wave-tiles
#define HBLK   (NPW / 4)                 // 8224 hash blocks (4 waves each)
#define PBLK   2048                      // prep blocks (4 cls rows each; 256 conv elems)
#define WS_C   (3 * HBLK)                // cls partial offset (doubles)
#define HBF_BYTES (NPTS * BITS * 2)      // 1 MiB bf16 H
#define SCALE  0.84932184f               // sqrt(0.5*log2 e): acc = theta*log2(e)
#define LN2    0.6931471805599453

// ws layout: bytes [0,1MiB): Hb. doubles after:
//   [0,HBLK) sp_all | [HBLK,2H) sp_same | [2H,3H) th_same | [WS_C, WS_C+PBLK) cls

typedef short    bf16x8   __attribute__((ext_vector_type(8)));
typedef unsigned short ushort8v __attribute__((ext_vector_type(8)));
typedef float    f32x16   __attribute__((ext_vector_type(16)));

__device__ __forceinline__ unsigned short f2bf(float f) {
    unsigned int u = __float_as_uint(f);
    u += 0x7FFFu + ((u >> 16) & 1u);     // RNE (inputs finite)
    return (unsigned short)(u >> 16);
}

// ---------------------------------------------------------------------------
// Prep: convert H -> scaled bf16 (1 elem/thread) + one log-softmax row/wave.
// ---------------------------------------------------------------------------
__global__ __launch_bounds__(256) void prep_kernel(const float* __restrict__ H,
                                                   const float* __restrict__ X,
                                                   const int* __restrict__ tgt,
                                                   unsigned short* __restrict__ Hb,
                                                   double* __restrict__ ws) {
    const int tid = threadIdx.x;
    const size_t t = (size_t)blockIdx.x * 256 + tid;
    Hb[t] = f2bf(H[t] * SCALE);

    const int lane = tid & 63, wave = tid >> 6;
    __shared__ float wsum[4];
    const int row = blockIdx.x * 4 + wave;          // exactly 8192 rows
    const float* x = X + (size_t)row * NCLS;
    float x1 = x[lane];
    float x2 = (lane + 64 < NCLS) ? x[lane + 64] : -INFINITY;
    float m = fmaxf(x1, x2);
#pragma unroll
    for (int d = 32; d > 0; d >>= 1) m = fmaxf(m, __shfl_xor(m, d, 64));
    float e = __expf(x1 - m) + ((lane + 64 < NCLS) ? __expf(x2 - m) : 0.f);
#pragma unroll
    for (int d = 32; d > 0; d >>= 1) e += __shfl_xor(e, d, 64);
    if (lane == 0) wsum[wave] = m + __logf(e) - x[tgt[row]];
    __syncthreads();
    if (tid == 0) {
        ws[WS_C + blockIdx.x] = (double)wsum[0] + (double)wsum[1]
                              + (double)wsum[2] + (double)wsum[3];
    }
}

// ---------------------------------------------------------------------------
// Hash: one independent 32x32 upper-tri tile per WAVE. 4 waves/block, no
// shared staging; fragments loaded directly from global bf16 (L1/L2-hot).
// ---------------------------------------------------------------------------
__global__ __launch_bounds__(256, 6) void hash_kernel(const unsigned short* __restrict__ HB,
                                                      const int* __restrict__ tgt,
                                                      double* __restrict__ ws) {
    const int tid = threadIdx.x, lane = tid & 63, wave = tid >> 6;
    const int p = blockIdx.x * 4 + wave;            // wave-tile id, < NPW

    // p -> (ti, tj), ti <= tj over NT2 rows
    int ti;
    {
        float disc = (2.0f * NT2 + 1.0f) * (2.0f * NT2 + 1.0f) - 8.0f * (float)p;
        ti = (int)(((2.0f * NT2 + 1.0f) - sqrtf(disc)) * 0.5f);
        if (ti < 0) ti = 0;
        if (ti >= NT2) ti = NT2 - 1;
        while (ti > 0 && (ti * NT2 - ti * (ti - 1) / 2) > p) ti--;
        while ((ti + 1) * NT2 - (ti + 1) * ti / 2 <= p) ti++;
    }
    const int tj = ti + (p - (ti * NT2 - ti * (ti - 1) / 2));
    const int i0 = ti * WT, j0 = tj * WT;

    const int lrow = lane & 31, hi = lane >> 5;
    const ushort8v* pA = (const ushort8v*)(HB + (size_t)(i0 + lrow) * BITS + hi * 8);
    const ushort8v* pB = (const ushort8v*)(HB + (size_t)(j0 + lrow) * BITS + hi * 8);

    bf16x8 fa[4], fb[4];
#pragma unroll
    for (int ks = 0; ks < 4; ++ks) {                // chunk ks*2+hi -> +ks*32B
        fa[ks] = __builtin_bit_cast(bf16x8, pA[ks * 2]);
        fb[ks] = __builtin_bit_cast(bf16x8, pB[ks * 2]);
    }

    f32x16 c;
#pragma unroll
    for (int e = 0; e < 16; ++e) c[e] = 0.f;
#pragma unroll
    for (int ks = 0; ks < 4; ++ks)
        c = __builtin_amdgcn_mfma_f32_32x32x16_bf16(fa[ks], fb[ks], c, 0, 0, 0);

    // C layout: col = lane&31, local row = (r&3) + 8*(r>>2) + 4*hi
    const int tc = tgt[j0 + lrow];
    float s_all = 0.f, s_same = 0.f, t_same = 0.f;
    if (ti != tj) {
#pragma unroll
        for (int r = 0; r < 16; ++r) {
            const int rowl = (r & 3) + 8 * (r >> 2) + 4 * hi;
            const int tr = tgt[i0 + rowl];
            float t0 = c[r];                         // theta*log2e
            float l0 = __log2f(1.f + exp2f(t0));     // softplus/ln2
            s_all += l0;
            float m0 = (tr == tc) ? 1.f : 0.f;
            s_same = fmaf(m0, l0, s_same);
            t_same = fmaf(m0, t0, t_same);
        }
    } else {
#pragma unroll
        for (int r = 0; r < 16; ++r) {
            const int rowl = (r & 3) + 8 * (r >> 2) + 4 * hi;
            const int tr = tgt[i0 + rowl];
            float t0 = c[r];
            float l0 = __log2f(1.f + exp2f(t0));
            bool v0 = lrow > rowl;                   // i<j within diagonal tile
            s_all += v0 ? l0 : 0.f;
            float m0 = (v0 && tr == tc) ? 1.f : 0.f;
            s_same = fmaf(m0, l0, s_same);
            t_same = fmaf(m0, t0, t_same);
        }
    }

#pragma unroll
    for (int d = 32; d > 0; d >>= 1) {
        s_all  += __shfl_xor(s_all,  d, 64);
        s_same += __shfl_xor(s_same, d, 64);
        t_same += __shfl_xor(t_same, d, 64);
    }
    __shared__ double red[12];
    if (lane == 0) {
        red[wave * 3 + 0] = (double)s_all;
        red[wave * 3 + 1] = (double)s_same;
        red[wave * 3 + 2] = (double)t_same;
    }
    __syncthreads();
    if (tid == 0) {
        ws[blockIdx.x]            = red[0] + red[3] + red[6] + red[9];
        ws[HBLK + blockIdx.x]     = red[1] + red[4] + red[7] + red[10];
        ws[2 * HBLK + blockIdx.x] = red[2] + red[5] + red[8] + red[11];
    }
}

// ---------------------------------------------------------------------------
// Finalize: histogram -> S0/S1 weights; double reduction; ln2 fold; 3 scalars.
// ---------------------------------------------------------------------------
__global__ __launch_bounds__(256) void final_kernel(const int* __restrict__ tgt,
                                                    const double* __restrict__ ws,
                                                    float* __restrict__ out) {
    __shared__ int hist[NCLS];
    __shared__ double r0[256], r1[256], r2[256], rc[256];
    const int tid = threadIdx.x;

    for (int i = tid; i < NCLS; i += 256) hist[i] = 0;
    __syncthreads();
    for (int i = tid; i < NPTS; i += 256) atomicAdd(&hist[tgt[i]], 1);
    __syncthreads();

    double a = 0.0, s = 0.0, t = 0.0, c = 0.0;
    for (int i = tid; i < HBLK; i += 256) {
        a += ws[i];
        s += ws[HBLK + i];
        t += ws[2 * HBLK + i];
    }
    for (int i = tid; i < PBLK; i += 256) c += ws[WS_C + i];
    r0[tid] = a; r1[tid] = s; r2[tid] = t; rc[tid] = c;
    __syncthreads();
    for (int sdt = 128; sdt > 0; sdt >>= 1) {
        if (tid < sdt) {
            r0[tid] += r0[tid + sdt];
            r1[tid] += r1[tid + sdt];
            r2[tid] += r2[tid + sdt];
            rc[tid] += rc[tid + sdt];
        }
        __syncthreads();
    }

    if (tid == 0) {
        double n_pos = 0.0;
        for (int k = 0; k < NCLS; k++) {
            double cc = (double)hist[k];
            n_pos += cc * cc;
        }
        const double Nd = (double)NPTS;
        double S1 = n_pos - Nd;
        double S0 = Nd * Nd - n_pos;
        if (S0 == 0.0) S0 = 1.0;
        if (S1 == 0.0) S1 = 1.0;
        const double S = S0 + S1;
        const double sum_lower = ((S / S0) * (r0[0] - r1[0]) + (S / S1) * (r1[0] - r2[0])) * LN2;
        const double count = Nd * (Nd - 1.0) * 0.5;
        const double hash_loss = sum_lower / count;
        const double cls_loss  = rc[0] / Nd;
        const double loss = 1.0 * cls_loss + 0.01 * hash_loss;
        out[0] = (float)hash_loss;
        out[1] = (float)cls_loss;
        out[2] = (float)loss;
    }
}

// ---------------------------------------------------------------------------
extern "C" void kernel_launch(void* const* d_in, const int* in_sizes, int n_in,
                              void* d_out, int out_size, void* d_ws, size_t ws_size,
                              hipStream_t stream) {
    const float* H   = (const float*)d_in[0];   // hash_out [8192,64]
    const float* X   = (const float*)d_in[1];   // cls_out  [8192,101]
    const int*   tgt = (const int*)d_in[2];     // target   [8192]
    float* out = (float*)d_out;

    unsigned short* Hb = (unsigned short*)d_ws;
    double* wsd = (double*)((char*)d_ws + HBF_BYTES);

    prep_kernel<<<PBLK, 256, 0, stream>>>(H, X, tgt, Hb, wsd);
    hash_kernel<<<HBLK, 256, 0, stream>>>(Hb, tgt, wsd);
    final_kernel<<<1, 256, 0, stream>>>(tgt, wsd, out);
}

// Round 6
// 56.678 us; speedup vs baseline: 1.1163x; 1.1163x over previous
//
#include <hip/hip_runtime.h>
#include <math.h>

#define NPTS   8192
#define BITS   64
#define NCLS   101
#define SCALE  0.84932184f              // sqrt(0.5*log2 e): acc = theta*log2(e)
#define LN2    0.6931471805599453

#define GX     256                      // i-tiles (32 rows each)
#define NSLOT  (GX * 16 * 4)            // 16384 strip wave-slots

// ws layout (bytes):
#define OFF_HB   0u                     // bf16 Hb [8192*64], class-sorted, scaled
#define OFF_PART (1u << 20)             // float4 [NSLOT]: {s_all, s_same, t_same, 0}
#define OFF_CLSP (OFF_PART + NSLOT*16u) // double [256]: cls NLL partials
#define OFF_SCLS (OFF_CLSP + 256u*8u)   // int [8192]: sorted class ids
#define OFF_BASE (OFF_SCLS + 8192u*4u)  // int [102]: class prefix
#define OFF_CNT  (OFF_BASE + 512u)      // int [101]: scatter counters

typedef short    bf16x8   __attribute__((ext_vector_type(8)));
typedef unsigned short ushort8v __attribute__((ext_vector_type(8)));
typedef float    f32x16   __attribute__((ext_vector_type(16)));

__device__ __forceinline__ unsigned short f2bf(float f) {
    unsigned int u = __float_as_uint(f);
    u += 0x7FFFu + ((u >> 16) & 1u);     // RNE (inputs finite)
    return (unsigned short)(u >> 16);
}
__device__ __forceinline__ float fexp2(float x) {
    float r; asm("v_exp_f32 %0, %1" : "=v"(r) : "v"(x)); return r;
}
__device__ __forceinline__ float flog2(float x) {
    float r; asm("v_log_f32 %0, %1" : "=v"(r) : "v"(x)); return r;
}

// ---------------------------------------------------------------------------
// K1: class histogram + prefix; zero scatter counters.
// ---------------------------------------------------------------------------
__global__ __launch_bounds__(1024) void hist_kernel(const int* __restrict__ tgt,
                                                    int* __restrict__ gbase,
                                                    int* __restrict__ gcnt) {
    __shared__ int hist[NCLS];
    const int tid = threadIdx.x;
    if (tid < NCLS) hist[tid] = 0;
    __syncthreads();
    for (int i = tid; i < NPTS; i += 1024) atomicAdd(&hist[tgt[i]], 1);
    __syncthreads();
    if (tid == 0) {
        int run = 0;
        for (int c = 0; c < NCLS; ++c) { gbase[c] = run; run += hist[c]; }
        gbase[NCLS] = run;
    }
    if (tid < NCLS) gcnt[tid] = 0;
}

// ---------------------------------------------------------------------------
// K2: scatter rows into class-sorted order; fp32 -> scaled bf16 convert.
// 64 blocks x 128 rows. Rank via per-class global atomics (order within a
// class is arbitrary; the pair SET — hence the loss — is invariant).
// ---------------------------------------------------------------------------
__global__ __launch_bounds__(256) void scatter_kernel(const float* __restrict__ H,
                                                      const int* __restrict__ tgt,
                                                      const int* __restrict__ gbase,
                                                      int* __restrict__ gcnt,
                                                      unsigned short* __restrict__ Hb,
                                                      int* __restrict__ scls) {
    __shared__ int rnk[128];
    const int tid = threadIdx.x;
    const int row0 = blockIdx.x * 128;
    if (tid < 128) {
        const int i = row0 + tid;
        const int c = tgt[i];
        const int r = gbase[c] + atomicAdd(&gcnt[c], 1);
        rnk[tid] = r;
        scls[r] = c;
    }
    __syncthreads();
#pragma unroll
    for (int s = 0; s < 32; ++s) {       // 32*256 = 8192 elems = 128 rows x 64
        const int flat = s * 256 + tid;
        const int lr = flat >> 6, d = flat & 63;
        const float v = H[(size_t)(row0 + lr) * BITS + d];
        Hb[(size_t)rnk[lr] * BITS + d] = f2bf(v * SCALE);
    }
}

// ---------------------------------------------------------------------------
// K3: hash strips + cls. grid (256, 17). y<16: hash — wave w owns a 32x128
// strip (i-tile = blockIdx.x, j-strip = y*4+w), 4 j-tiles with A reuse.
// Sorted classes => ~95% of tiles need NO tgt access and NO masks.
// y==16: one block per i-tile does 32 rows of log-softmax NLL.
// ---------------------------------------------------------------------------
__global__ __launch_bounds__(256, 6) void hash_kernel(const unsigned short* __restrict__ HB,
                                                      const float* __restrict__ X,
                                                      const int* __restrict__ tgt,
                                                      const int* __restrict__ scls,
                                                      float4* __restrict__ part,
                                                      double* __restrict__ clsp) {
    __shared__ float wsum[4];
    const int tid = threadIdx.x, lane = tid & 63, wave = tid >> 6;
    const int ti = blockIdx.x;

    if (blockIdx.y == 16) {              // ---- cls slice ----
        float acc = 0.f;
#pragma unroll
        for (int rr = 0; rr < 8; ++rr) {
            const int row = ti * 32 + wave * 8 + rr;
            const float* x = X + (size_t)row * NCLS;
            float x1 = x[lane];
            float x2 = (lane + 64 < NCLS) ? x[lane + 64] : -INFINITY;
            float m = fmaxf(x1, x2);
#pragma unroll
            for (int d = 32; d > 0; d >>= 1) m = fmaxf(m, __shfl_xor(m, d, 64));
            float e = __expf(x1 - m) + ((lane + 64 < NCLS) ? __expf(x2 - m) : 0.f);
#pragma unroll
            for (int d = 32; d > 0; d >>= 1) e += __shfl_xor(e, d, 64);
            if (lane == 0) acc += m + __logf(e) - x[tgt[row]];
        }
        if (lane == 0) wsum[wave] = acc;
        __syncthreads();
        if (tid == 0)
            clsp[ti] = (double)wsum[0] + (double)wsum[1]
                     + (double)wsum[2] + (double)wsum[3];
        return;
    }

    // ---- hash strip ----
    const int i0 = ti * 32;
    const int jstrip = blockIdx.y * 4 + wave;
    const int slot = (ti * 16 + blockIdx.y) * 4 + wave;
    if (jstrip * 128 + 96 < i0) {        // strip entirely below diagonal
        if (lane == 0) part[slot] = make_float4(0.f, 0.f, 0.f, 0.f);
        return;
    }

    const int lrow = lane & 31, hi = lane >> 5;
    const ushort8v* pA = (const ushort8v*)(HB + (size_t)(i0 + lrow) * BITS + hi * 8);
    bf16x8 fa[4];
#pragma unroll
    for (int ks = 0; ks < 4; ++ks) fa[ks] = __builtin_bit_cast(bf16x8, pA[ks * 2]);
    const int ci_hi = scls[i0 + 31];

    float s_all = 0.f, s_same = 0.f, t_same = 0.f;
    for (int jt = 0; jt < 4; ++jt) {
        const int j0 = jstrip * 128 + jt * 32;
        if (j0 < i0) continue;

        const ushort8v* pB = (const ushort8v*)(HB + (size_t)(j0 + lrow) * BITS + hi * 8);
        bf16x8 fb[4];
#pragma unroll
        for (int ks = 0; ks < 4; ++ks) fb[ks] = __builtin_bit_cast(bf16x8, pB[ks * 2]);

        f32x16 cc;
#pragma unroll
        for (int e = 0; e < 16; ++e) cc[e] = 0.f;
#pragma unroll
        for (int ks = 0; ks < 4; ++ks)
            cc = __builtin_amdgcn_mfma_f32_32x32x16_bf16(fa[ks], fb[ks], cc, 0, 0, 0);

        // C layout: col = lane&31, local row = (r&3)+8*(r>>2)+4*hi
        const bool needSame = (scls[j0] <= ci_hi);   // class ranges overlap
        if (!needSame) {                              // hot path: no masks, no tgt
#pragma unroll
            for (int r = 0; r < 16; ++r)
                s_all += flog2(1.f + fexp2(cc[r]));
        } else {
            const bool isDiag = (j0 == i0);
            const int tc = scls[j0 + lrow];
#pragma unroll
            for (int r = 0; r < 16; ++r) {
                const int rowl = (r & 3) + 8 * (r >> 2) + 4 * hi;
                const int tr = scls[i0 + rowl];
                const float t0 = cc[r];
                const float l = flog2(1.f + fexp2(t0));
                const bool v = isDiag ? (lrow > rowl) : true;
                s_all += v ? l : 0.f;
                const float m = (v && tr == tc) ? 1.f : 0.f;
                s_same = fmaf(m, l, s_same);
                t_same = fmaf(m, t0, t_same);
            }
        }
    }

#pragma unroll
    for (int d = 32; d > 0; d >>= 1) {
        s_all  += __shfl_xor(s_all,  d, 64);
        s_same += __shfl_xor(s_same, d, 64);
        t_same += __shfl_xor(t_same, d, 64);
    }
    if (lane == 0) part[slot] = make_float4(s_all, s_same, t_same, 0.f);
}

// ---------------------------------------------------------------------------
// K4: finalize. n_pos from class counts; double reduction; ln2 fold.
// ---------------------------------------------------------------------------
__global__ __launch_bounds__(1024) void final_kernel(const int* __restrict__ gbase,
                                                     const float4* __restrict__ part,
                                                     const double* __restrict__ clsp,
                                                     float* __restrict__ out) {
    __shared__ double r0[1024], r1[1024], r2[1024], rc[1024];
    const int tid = threadIdx.x;

    double a = 0.0, s = 0.0, t = 0.0, c = 0.0;
    for (int i = tid; i < NSLOT; i += 1024) {
        const float4 v = part[i];
        a += (double)v.x; s += (double)v.y; t += (double)v.z;
    }
    if (tid < 256) c = clsp[tid];
    r0[tid] = a; r1[tid] = s; r2[tid] = t; rc[tid] = c;
    __syncthreads();
    for (int sd = 512; sd > 0; sd >>= 1) {
        if (tid < sd) {
            r0[tid] += r0[tid + sd];
            r1[tid] += r1[tid + sd];
            r2[tid] += r2[tid + sd];
            rc[tid] += rc[tid + sd];
        }
        __syncthreads();
    }

    if (tid == 0) {
        double n_pos = 0.0;
        for (int k = 0; k < NCLS; ++k) {
            const double ck = (double)(gbase[k + 1] - gbase[k]);
            n_pos += ck * ck;
        }
        const double Nd = (double)NPTS;
        double S1 = n_pos - Nd;
        double S0 = Nd * Nd - n_pos;
        if (S0 == 0.0) S0 = 1.0;
        if (S1 == 0.0) S1 = 1.0;
        const double S = S0 + S1;
        const double sum_lower =
            ((S / S0) * (r0[0] - r1[0]) + (S / S1) * (r1[0] - r2[0])) * LN2;
        const double count = Nd * (Nd - 1.0) * 0.5;
        const double hash_loss = sum_lower / count;
        const double cls_loss  = rc[0] / Nd;
        const double loss = 1.0 * cls_loss + 0.01 * hash_loss;
        out[0] = (float)hash_loss;
        out[1] = (float)cls_loss;
        out[2] = (float)loss;
    }
}

// ---------------------------------------------------------------------------
extern "C" void kernel_launch(void* const* d_in, const int* in_sizes, int n_in,
                              void* d_out, int out_size, void* d_ws, size_t ws_size,
                              hipStream_t stream) {
    const float* H   = (const float*)d_in[0];   // hash_out [8192,64]
    const float* X   = (const float*)d_in[1];   // cls_out  [8192,101]
    const int*   tgt = (const int*)d_in[2];     // target   [8192]
    float* out = (float*)d_out;

    char* w = (char*)d_ws;
    unsigned short* Hb   = (unsigned short*)(w + OFF_HB);
    float4*         prt  = (float4*)(w + OFF_PART);
    double*         clsp = (double*)(w + OFF_CLSP);
    int*            scls = (int*)(w + OFF_SCLS);
    int*            base = (int*)(w + OFF_BASE);
    int*            cnt  = (int*)(w + OFF_CNT);

    hist_kernel<<<1, 1024, 0, stream>>>(tgt, base, cnt);
    scatter_kernel<<<64, 256, 0, stream>>>(H, tgt, base, cnt, Hb, scls);
    hash_kernel<<<dim3(GX, 17), 256, 0, stream>>>(Hb, X, tgt, scls, prt, clsp);
    final_kernel<<<1, 1024, 0, stream>>>(base, prt, clsp, out);
}